// Round 12
// baseline (392.801 us; speedup 1.0000x reference)
//
#include <hip/hip_runtime.h>
#include <hip/hip_bf16.h>
#include <stdint.h>

// ---------------------------------------------------------------------------
// ChebConv with attention + per-(t,k) dropout, MI355X bf16 MFMA implementation
// out[b,t,u,o] = relu( sum_k M[t,k] @ x[b,t] @ Theta[k] )   (associativity!)
// R12: precompute y_k = x @ Theta_k  ->  out = [M_0 M_1 M_2] @ [y_0;y_1;y_2],
// a single K=3072 GEMM. Kills pacc[3] (->64 AGPR), kills stage-2, enables
// 64x64 wave tiles (FLOP/B 21->32; R8-R11 were data-pipe-bound at 27-33%).
// A = Mf fragment-order VGPR-direct (depth-2 reg prefetch under the burst,
// 4 wave-cols share addrs -> L1 broadcast). B = yt staged in LDS (32KB dbuf,
// R3-verified XOR swizzle). LDS 64KB -> 2 blocks/CU.
// ws: Mf 75.5MB | yt 144MB (full) = 226.5MB; runtime fallback: 4 b-quarter
// passes with yt 36MB (total 113MB, proven budget), same kernels.
// mask = threefry2x32 partitionable, key(42), bits = x0^x1   (verified R0)
// ---------------------------------------------------------------------------

typedef __attribute__((ext_vector_type(8))) short short8;
typedef __attribute__((ext_vector_type(4))) float f32x4;

__device__ __forceinline__ ushort f2bf(float f) {
  __hip_bfloat16 h = __float2bfloat16(f);
  return *reinterpret_cast<ushort*>(&h);
}

__device__ __forceinline__ short8 cvt8(float4 a, float4 b) {
  short8 r;
  r[0] = (short)f2bf(a.x); r[1] = (short)f2bf(a.y);
  r[2] = (short)f2bf(a.z); r[3] = (short)f2bf(a.w);
  r[4] = (short)f2bf(b.x); r[5] = (short)f2bf(b.y);
  r[6] = (short)f2bf(b.z); r[7] = (short)f2bf(b.w);
  return r;
}

__device__ __forceinline__ void threefry2x32(uint32_t c0, uint32_t c1,
                                             uint32_t& o0, uint32_t& o1) {
  const uint32_t ks0 = 0u;
  const uint32_t ks1 = 42u;
  const uint32_t ks2 = ks0 ^ ks1 ^ 0x1BD11BDAu;
  uint32_t x0 = c0 + ks0;
  uint32_t x1 = c1 + ks1;
#define TFR(r) { x0 += x1; x1 = (x1 << (r)) | (x1 >> (32 - (r))); x1 ^= x0; }
  TFR(13) TFR(15) TFR(26) TFR(6)
  x0 += ks1; x1 += ks2 + 1u;
  TFR(17) TFR(29) TFR(16) TFR(24)
  x0 += ks2; x1 += ks0 + 2u;
  TFR(13) TFR(15) TFR(26) TFR(6)
  x0 += ks0; x1 += ks1 + 3u;
  TFR(17) TFR(29) TFR(16) TFR(24)
  x0 += ks1; x1 += ks2 + 4u;
  TFR(13) TFR(15) TFR(26) TFR(6)
  x0 += ks2; x1 += ks0 + 5u;
#undef TFR
  o0 = x0; o1 = x1;
}

// ---------------------------------------------------------------------------
// Kernel 1: build masked M (bf16) in MFMA-fragment order (verified R11).
// idx = (((tk*64+u16)*16+vc)*2+ks)*512 + lane*8 + j;
// u = u16*16+(lane&15), v = vc*64+ks*32+(lane>>4)*8+j.
// ---------------------------------------------------------------------------
__global__ void build_m(const float* __restrict__ Att,
                        const float* __restrict__ cheb,
                        ushort* __restrict__ Mf) {
  const uint32_t idx = blockIdx.x * 256u + threadIdx.x;
  const uint32_t j = idx & 7u;
  const uint32_t lane = (idx >> 3) & 63u;
  const uint32_t ks = (idx >> 9) & 1u;
  const uint32_t c = (idx >> 10) & 15u;
  const uint32_t u16 = (idx >> 14) & 63u;
  const uint32_t tk = idx >> 20;
  const uint32_t up = u16 * 16u + (lane & 15u);
  const uint32_t vp = c * 64u + ks * 32u + (lane >> 4) * 8u + j;
  float val = 0.f;
  if ((vp < 1000u) & (up < 1000u)) {
    const uint32_t flat = (tk * 1000u + up) * 1000u + vp;
    uint32_t o0, o1;
    threefry2x32(0u, flat, o0, o1);
    const uint32_t bits = o0 ^ o1;
    const float u = __uint_as_float((bits >> 9) | 0x3f800000u) - 1.0f;
    if (u < 0.4f) {
      val = cheb[(tk % 3u) * 1000000u + up * 1000u + vp] *
            Att[up * 1000u + vp] * 2.5f;
    }
  }
  Mf[idx] = f2bf(val);
}

// ---------------------------------------------------------------------------
// Kernel 2: build_yt -- y_k[b,t] = x[b,t] @ Theta_k, stored transposed:
// yt[k][t][nrow=(b-bq0)*64+o][v pad 1024] bf16.
// Block 192 thr (3 waves), block = (vc, t, bb); wave w computes k=w:
// C[o][v] (64x64) = ThetaT (A, LDS) @ x-rows (B, global f32->bf16).
// Store via wave-local LDS transpose (rows of 64 v, 128B coalesced).
// ---------------------------------------------------------------------------
#define MFMA(a, b, c) __builtin_amdgcn_mfma_f32_16x16x32_bf16((a), (b), (c), 0, 0, 0)

__global__ __launch_bounds__(192, 1)
void build_yt(const float* __restrict__ x, const float* __restrict__ Theta,
              ushort* __restrict__ yt, int NR, int bq0) {
  __shared__ __align__(16) ushort sm[13824];  // sTh [3][64][72]; sY overlays
  const int tid = threadIdx.x, lane = tid & 63, w = tid >> 6;
  const int quad = lane >> 4, l15 = lane & 15;
  const int vc = blockIdx.x, t = blockIdx.y, bb = blockIdx.z;
  const int b = bq0 + bb;
  const int v0 = vc * 64;

  // stage ThetaT: sTh[k][o][f] = Theta[k][f][o]
  for (int e = tid; e < 12288; e += 192) {
    const int k = e >> 12, rem = e & 4095, f = rem >> 6, o = rem & 63;
    sm[k * 4608 + o * 72 + f] = f2bf(Theta[e]);
  }
  __syncthreads();

  f32x4 pacc[4][4];
#pragma unroll
  for (int i = 0; i < 4; ++i)
#pragma unroll
    for (int j = 0; j < 4; ++j) pacc[i][j] = f32x4{0.f, 0.f, 0.f, 0.f};

  const ushort* sTh = sm + w * 4608;      // wave w reads only its own k slab
  const float* xb = x + (((size_t)b * 12 + t) * 1000) * 64;

#pragma unroll
  for (int ks = 0; ks < 2; ++ks) {
    short8 av[4], bv[4];
#pragma unroll
    for (int mi = 0; mi < 4; ++mi)
      av[mi] = *(const short8*)&sTh[(mi * 16 + l15) * 72 + ks * 32 + quad * 8];
#pragma unroll
    for (int ni = 0; ni < 4; ++ni) {
      const int v = v0 + ni * 16 + l15;
      float4 c0 = make_float4(0.f, 0.f, 0.f, 0.f);
      float4 c1 = make_float4(0.f, 0.f, 0.f, 0.f);
      if (v < 1000) {
        const float* row = xb + (size_t)v * 64 + ks * 32 + quad * 8;
        c0 = *(const float4*)row;
        c1 = *(const float4*)(row + 4);
      }
      bv[ni] = cvt8(c0, c1);
    }
#pragma unroll
    for (int mi = 0; mi < 4; ++mi)
#pragma unroll
      for (int ni = 0; ni < 4; ++ni)
        pacc[mi][ni] = MFMA(av[mi], bv[ni], pacc[mi][ni]);
  }

  // wave-local transpose: overlay own sTh slab (only this wave read it)
  ushort* sY = sm + w * 4608;
#pragma unroll
  for (int mi = 0; mi < 4; ++mi)
#pragma unroll
    for (int ni = 0; ni < 4; ++ni)
#pragma unroll
      for (int r = 0; r < 4; ++r)
        sY[(mi * 16 + quad * 4 + r) * 72 + ni * 16 + l15] = f2bf(pacc[mi][ni][r]);

  // store rows (same wave; ds ordering guaranteed by lgkmcnt)
  const int seg = lane & 7;
#pragma unroll
  for (int p = 0; p < 8; ++p) {
    const int o = p * 8 + (lane >> 3);
    const uint4 val = *(const uint4*)&sY[o * 72 + seg * 8];
    *(uint4*)(yt + (((size_t)(w * 12 + t) * (size_t)NR + (size_t)bb * 64 + o) << 10)
                 + v0 + seg * 8) = val;
  }
}

// ---------------------------------------------------------------------------
// Kernel 3: the K=3072 GEMM. 512 thr (8 waves, 2x4), block 128u x 256n per t,
// wave tile 64x64. 48 chunks of K=64 (kk=c>>4 selects y_k slab).
// A: Mf VGPR-direct, ping-pong prefetch (aA/aB) issued before the burst.
// B: yt staged in LDS dbuf (2x32KB), XOR content swizzle, p/q reg ping-pong.
// Epilogue: relu + f32 store straight from pacc.
// ---------------------------------------------------------------------------
#define LOAD_A(AR, C)                                                         \
  do {                                                                        \
    const size_t base_ = ((tk3 + (size_t)((C) >> 4)) << 20) +                 \
                         ((size_t)((C) & 15) << 10) + lane * 8;               \
    _Pragma("unroll")                                                         \
    for (int mi = 0; mi < 4; ++mi)                                            \
      _Pragma("unroll")                                                       \
      for (int ks = 0; ks < 2; ++ks)                                          \
        AR[mi][ks] = *(const short8*)(Mf + base_ +                            \
                       ((size_t)(u16b + mi) << 14) + (ks << 9));              \
  } while (0)

#define LOAD_B(P0, P1, P2, P3, C)                                             \
  do {                                                                        \
    const size_t yb_ = (((size_t)(((C) >> 4) * 12 + t) * (size_t)NR + n0 +    \
                         brow) << 10) + ((size_t)((C) & 15) << 6) + gch * 8;  \
    P0 = *(const uint4*)(yt + yb_);                                           \
    P1 = *(const uint4*)(yt + yb_ + (64 << 10));                              \
    P2 = *(const uint4*)(yt + yb_ + (128 << 10));                             \
    P3 = *(const uint4*)(yt + yb_ + (192 << 10));                             \
  } while (0)

#define WRITE_B(P0, P1, P2, P3, BUF)                                          \
  do {                                                                        \
    *(uint4*)&(BUF)[tid * 8]          = P0;                                   \
    *(uint4*)&(BUF)[4096 + tid * 8]   = P1;                                   \
    *(uint4*)&(BUF)[8192 + tid * 8]   = P2;                                   \
    *(uint4*)&(BUF)[12288 + tid * 8]  = P3;                                   \
  } while (0)

#define BURST(BUF, AR)                                                        \
  do {                                                                        \
    _Pragma("unroll")                                                         \
    for (int ks = 0; ks < 2; ++ks) {                                          \
      short8 bv[4];                                                           \
      _Pragma("unroll")                                                       \
      for (int ni = 0; ni < 4; ++ni) {                                        \
        const int row_ = wc * 64 + ni * 16 + l15;                             \
        bv[ni] = *(const short8*)&(BUF)[row_ * 64 +                           \
                                        ((((ks * 4 + quad) ^ rsw)) << 3)];    \
      }                                                                       \
      _Pragma("unroll")                                                       \
      for (int mi = 0; mi < 4; ++mi)                                          \
        _Pragma("unroll")                                                     \
        for (int ni = 0; ni < 4; ++ni)                                        \
          pacc[mi][ni] = MFMA(AR[mi][ks], bv[ni], pacc[mi][ni]);              \
    }                                                                         \
  } while (0)

__global__ __launch_bounds__(512, 2)
void gemm_main(const ushort* __restrict__ Mf, const ushort* __restrict__ yt,
               float* __restrict__ out, int NR, int bq0, int nblocks) {
  __shared__ __align__(16) ushort smem[32768];  // buf0 | buf1 (32KB each)
  const int tid = threadIdx.x, lane = tid & 63, w = tid >> 6;
  const int wr = w >> 2, wc = w & 3;            // 2 x 4 wave grid
  const int quad = lane >> 4, l15 = lane & 15, rsw = l15 & 7;
  // XCD-bijective decode (nblocks % 8 == 0): contiguous swz share (t,ut)
  const int q = nblocks >> 3;
  const int swz = ((int)blockIdx.x & 7) * q + ((int)blockIdx.x >> 3);
  const int ntcnt = NR >> 8;
  const int ntile = swz % ntcnt;
  const int rem = swz / ntcnt;
  const int ut = rem & 7, t = rem >> 3;
  const int u0 = ut * 128, n0 = ntile * 256;

  ushort* buf0 = smem;
  ushort* buf1 = smem + 16384;

  const int gch = (tid & 7) ^ ((tid >> 3) & 7);  // pre-swizzled source chunk
  const int brow = tid >> 3;                     // staging base row (0..63)
  const int u16b = ut * 8 + wr * 4;
  const size_t tk3 = (size_t)(t * 3);

  f32x4 pacc[4][4];
#pragma unroll
  for (int i = 0; i < 4; ++i)
#pragma unroll
    for (int j = 0; j < 4; ++j) pacc[i][j] = f32x4{0.f, 0.f, 0.f, 0.f};

  short8 aA[4][2], aB[4][2];
  uint4 p0, p1, p2, p3, q0, q1, q2, q3;

  // prologue: B(0)->buf0, A(0)->aA
  LOAD_B(p0, p1, p2, p3, 0);
  WRITE_B(p0, p1, p2, p3, buf0);
  LOAD_A(aA, 0);
  __syncthreads();

#pragma unroll 1
  for (int it = 0; it < 24; ++it) {
    const int c1 = it * 2 + 1;
    // even chunk: burst buf0/aA; prefetch chunk+1 (A->aB, B->q)
    LOAD_A(aB, it * 2 + 1);
    LOAD_B(q0, q1, q2, q3, it * 2 + 1);
    __builtin_amdgcn_s_setprio(1);
    BURST(buf0, aA);
    __builtin_amdgcn_s_setprio(0);
    WRITE_B(q0, q1, q2, q3, buf1);
    __syncthreads();
    // odd chunk: burst buf1/aB; prefetch chunk+1 (A->aA, B->p)
    if (c1 < 47) {
      LOAD_A(aA, c1 + 1);
      LOAD_B(p0, p1, p2, p3, c1 + 1);
    }
    __builtin_amdgcn_s_setprio(1);
    BURST(buf1, aB);
    __builtin_amdgcn_s_setprio(0);
    if (c1 < 47) WRITE_B(p0, p1, p2, p3, buf0);
    __syncthreads();
  }

  // epilogue: relu + f32 store (u rows of out, o contiguous per lane group)
  const int ubase = u0 + wr * 64;
  const int nbase = n0 + wc * 64;
#pragma unroll
  for (int mi = 0; mi < 4; ++mi)
#pragma unroll
    for (int ni = 0; ni < 4; ++ni) {
      const int n = nbase + ni * 16 + l15;
      const int b = bq0 + (n >> 6), o = n & 63;
      float* op = out + (((size_t)b * 12 + t) * 1000) * 64 + o;
#pragma unroll
      for (int r = 0; r < 4; ++r) {
        const int u = ubase + mi * 16 + quad * 4 + r;
        if (u < 1000) op[(size_t)u * 64] = fmaxf(pacc[mi][ni][r], 0.f);
      }
    }
}

// ---------------------------------------------------------------------------
extern "C" void kernel_launch(void* const* d_in, const int* in_sizes, int n_in,
                              void* d_out, int out_size, void* d_ws, size_t ws_size,
                              hipStream_t stream) {
  const float* x     = (const float*)d_in[0];
  const float* Att   = (const float*)d_in[1];
  const float* cheb  = (const float*)d_in[2];
  const float* Theta = (const float*)d_in[3];
  float* out = (float*)d_out;

  ushort* Mf = (ushort*)d_ws;            // 75.5 MB fragment-ordered M
  ushort* yt = Mf + 37748736ull;         // yt region

  build_m<<<147456, 256, 0, stream>>>(Att, cheb, Mf);

  if (ws_size >= 226492416ull) {
    // full path: yt [3][12][2048][1024] bf16 (144MB)
    build_yt<<<dim3(16, 12, 32), 192, 0, stream>>>(x, Theta, yt, 2048, 0);
    gemm_main<<<768, 512, 0, stream>>>(Mf, yt, out, 2048, 0, 768);
  } else {
    // quarter path: 4 passes of 8 batches, yt [3][12][512][1024] (36MB)
    for (int qq = 0; qq < 4; ++qq) {
      build_yt<<<dim3(16, 12, 8), 192, 0, stream>>>(x, Theta, yt, 512, qq * 8);
      gemm_main<<<192, 512, 0, stream>>>(Mf, yt, out, 512, qq * 8, 192);
    }
  }
}

// Round 13
// 377.395 us; speedup vs baseline: 1.0408x; 1.0408x over previous
//
#include <hip/hip_runtime.h>
#include <hip/hip_bf16.h>
#include <stdint.h>

// ---------------------------------------------------------------------------
// ChebConv with attention + per-(t,k) dropout, MI355X bf16 MFMA implementation
// out[b,t,u,o] = relu( sum_k M[t,k] @ x[b,t] @ Theta[k] )   (associativity)
// R13: keep R12's K=3072 single GEMM (y_k = x@Theta_k precomputed), but stage
// BOTH operands through LDS once per chunk (R12's VGPR-direct A cost 4x
// redundant L2 traffic -> data-pipe bound at 25%). Block 128u x 256n, 8 waves
// (2x4), wave 64x64, K-chunk 64, 96KB LDS dbuf. Per chunk: global 48KB
// (857cy L2), LDS 176KB (1375cy), MFMA 1241cy -> balanced ~90% ceiling.
// XCD swizzle groups the 8 ut-blocks of one (t,nt) per XCD -> B L2-reuse.
// mask = threefry2x32 partitionable, key(42), bits = x0^x1   (verified R0)
// ws: M row-major [36][1024][1024] bf16 (75.5MB) | yt [3][12][NR][1024] bf16
// ---------------------------------------------------------------------------

typedef __attribute__((ext_vector_type(8))) short short8;
typedef __attribute__((ext_vector_type(4))) float f32x4;

__device__ __forceinline__ ushort f2bf(float f) {
  __hip_bfloat16 h = __float2bfloat16(f);
  return *reinterpret_cast<ushort*>(&h);
}

__device__ __forceinline__ short8 cvt8(float4 a, float4 b) {
  short8 r;
  r[0] = (short)f2bf(a.x); r[1] = (short)f2bf(a.y);
  r[2] = (short)f2bf(a.z); r[3] = (short)f2bf(a.w);
  r[4] = (short)f2bf(b.x); r[5] = (short)f2bf(b.y);
  r[6] = (short)f2bf(b.z); r[7] = (short)f2bf(b.w);
  return r;
}

__device__ __forceinline__ void threefry2x32(uint32_t c0, uint32_t c1,
                                             uint32_t& o0, uint32_t& o1) {
  const uint32_t ks0 = 0u;
  const uint32_t ks1 = 42u;
  const uint32_t ks2 = ks0 ^ ks1 ^ 0x1BD11BDAu;
  uint32_t x0 = c0 + ks0;
  uint32_t x1 = c1 + ks1;
#define TFR(r) { x0 += x1; x1 = (x1 << (r)) | (x1 >> (32 - (r))); x1 ^= x0; }
  TFR(13) TFR(15) TFR(26) TFR(6)
  x0 += ks1; x1 += ks2 + 1u;
  TFR(17) TFR(29) TFR(16) TFR(24)
  x0 += ks2; x1 += ks0 + 2u;
  TFR(13) TFR(15) TFR(26) TFR(6)
  x0 += ks0; x1 += ks1 + 3u;
  TFR(17) TFR(29) TFR(16) TFR(24)
  x0 += ks1; x1 += ks2 + 4u;
  TFR(13) TFR(15) TFR(26) TFR(6)
  x0 += ks2; x1 += ks0 + 5u;
#undef TFR
  o0 = x0; o1 = x1;
}

// ---------------------------------------------------------------------------
// Kernel 1: build masked M (bf16) row-major padded [36][1024][1024] (R3-proven)
// ---------------------------------------------------------------------------
__global__ void build_m(const float* __restrict__ Att,
                        const float* __restrict__ cheb,
                        ushort* __restrict__ Mws) {
  const uint32_t idx = blockIdx.x * 256u + threadIdx.x;
  const uint32_t vp = idx & 1023u;
  const uint32_t up = (idx >> 10) & 1023u;
  const uint32_t tk = idx >> 20;
  float val = 0.f;
  if ((vp < 1000u) & (up < 1000u)) {
    const uint32_t flat = (tk * 1000u + up) * 1000u + vp;
    uint32_t o0, o1;
    threefry2x32(0u, flat, o0, o1);
    const uint32_t bits = o0 ^ o1;
    const float u = __uint_as_float((bits >> 9) | 0x3f800000u) - 1.0f;
    if (u < 0.4f) {
      val = cheb[(tk % 3u) * 1000000u + up * 1000u + vp] *
            Att[up * 1000u + vp] * 2.5f;
    }
  }
  Mws[idx] = f2bf(val);
}

// ---------------------------------------------------------------------------
// Kernel 2: build_yt -- y_k[b,t] = x[b,t] @ Theta_k, stored transposed:
// yt[k][t][nrow=(b-bq0)*64+o][v pad 1024] bf16.  (R12-proven math; now 8 vc
// per block to amortize Theta staging.)  192 thr (3 waves), wave w <-> k=w.
// ---------------------------------------------------------------------------
#define MFMA(a, b, c) __builtin_amdgcn_mfma_f32_16x16x32_bf16((a), (b), (c), 0, 0, 0)

__global__ __launch_bounds__(192, 1)
void build_yt(const float* __restrict__ x, const float* __restrict__ Theta,
              ushort* __restrict__ yt, int NR, int bq0) {
  __shared__ __align__(16) ushort sm[27648];  // sTh [0,13824) | sY [13824,..)
  const int tid = threadIdx.x, lane = tid & 63, w = tid >> 6;
  const int quad = lane >> 4, l15 = lane & 15;
  const int vh = blockIdx.x, t = blockIdx.y, bb = blockIdx.z;
  const int b = bq0 + bb;

  // stage ThetaT: sTh[k][o][f] = Theta[k][f][o]
  for (int e = tid; e < 12288; e += 192) {
    const int k = e >> 12, rem = e & 4095, f = rem >> 6, o = rem & 63;
    sm[k * 4608 + o * 72 + f] = f2bf(Theta[e]);
  }
  __syncthreads();

  const ushort* sTh = sm + w * 4608;           // wave-private k slab
  ushort* sY = sm + 13824 + w * 4608;          // wave-private transpose buf
  const float* xb = x + (((size_t)b * 12 + t) * 1000) * 64;
  const int seg = lane & 7;

#pragma unroll 1
  for (int vi = 0; vi < 8; ++vi) {
    const int vc = vh * 8 + vi;
    const int v0 = vc * 64;

    f32x4 pacc[4][4];
#pragma unroll
    for (int i = 0; i < 4; ++i)
#pragma unroll
      for (int j = 0; j < 4; ++j) pacc[i][j] = f32x4{0.f, 0.f, 0.f, 0.f};

#pragma unroll
    for (int ks = 0; ks < 2; ++ks) {
      short8 av[4], bv[4];
#pragma unroll
      for (int mi = 0; mi < 4; ++mi)
        av[mi] = *(const short8*)&sTh[(mi * 16 + l15) * 72 + ks * 32 + quad * 8];
#pragma unroll
      for (int ni = 0; ni < 4; ++ni) {
        const int v = v0 + ni * 16 + l15;
        float4 c0 = make_float4(0.f, 0.f, 0.f, 0.f);
        float4 c1 = make_float4(0.f, 0.f, 0.f, 0.f);
        if (v < 1000) {
          const float* row = xb + (size_t)v * 64 + ks * 32 + quad * 8;
          c0 = *(const float4*)row;
          c1 = *(const float4*)(row + 4);
        }
        bv[ni] = cvt8(c0, c1);
      }
#pragma unroll
      for (int mi = 0; mi < 4; ++mi)
#pragma unroll
        for (int ni = 0; ni < 4; ++ni)
          pacc[mi][ni] = MFMA(av[mi], bv[ni], pacc[mi][ni]);
    }

    // wave-local transpose (compiler orders ds_write->ds_read via lgkmcnt)
#pragma unroll
    for (int mi = 0; mi < 4; ++mi)
#pragma unroll
      for (int ni = 0; ni < 4; ++ni)
#pragma unroll
        for (int r = 0; r < 4; ++r)
          sY[(mi * 16 + quad * 4 + r) * 72 + ni * 16 + l15] = f2bf(pacc[mi][ni][r]);

#pragma unroll
    for (int p = 0; p < 8; ++p) {
      const int o = p * 8 + (lane >> 3);
      const uint4 val = *(const uint4*)&sY[o * 72 + seg * 8];
      *(uint4*)(yt + (((size_t)(w * 12 + t) * (size_t)NR + (size_t)bb * 64 + o) << 10)
                   + v0 + seg * 8) = val;
    }
  }
}

// ---------------------------------------------------------------------------
// Kernel 3: K=3072 GEMM, both operands LDS-staged.  512 thr (8 waves, 2x4),
// block 128u x 256n, wave 64x64, K-chunk 64.  Buffer = sA[128][64] (16KB) +
// sB[256][64] (32KB) = 48KB; double-buffered = 96KB.  6 named-reg 16B loads
// per thread per chunk, issue-early / write-late, __syncthreads per chunk.
// Content XOR-swizzle (verified): LDS[r][c16B] = G[r][c ^ (r&7)].
// Epilogue: relu + f32 store direct from pacc.
// ---------------------------------------------------------------------------

#define LOADCH(A0, A1, B0, B1, B2, B3, C)                                     \
  do {                                                                        \
    const size_t koA_ = ((size_t)((C) >> 4) << 20) + (size_t)(((C) & 15) << 6); \
    const size_t koB_ = (size_t)((C) >> 4) * ytk + (size_t)(((C) & 15) << 6); \
    A0 = *(const uint4*)(Mws + aA0 + koA_);                                   \
    A1 = *(const uint4*)(Mws + aA1 + koA_);                                   \
    B0 = *(const uint4*)(yt + bB0 + koB_);                                    \
    B1 = *(const uint4*)(yt + bB1 + koB_);                                    \
    B2 = *(const uint4*)(yt + bB2 + koB_);                                    \
    B3 = *(const uint4*)(yt + bB3 + koB_);                                    \
  } while (0)

#define WRITECH(A0, A1, B0, B1, B2, B3, BUF)                                  \
  do {                                                                        \
    *(uint4*)&(BUF)[(w * 2 + 0) * 512 + lane * 8]        = A0;                \
    *(uint4*)&(BUF)[(w * 2 + 1) * 512 + lane * 8]        = A1;                \
    *(uint4*)&(BUF)[8192 + (w * 4 + 0) * 512 + lane * 8] = B0;                \
    *(uint4*)&(BUF)[8192 + (w * 4 + 1) * 512 + lane * 8] = B1;                \
    *(uint4*)&(BUF)[8192 + (w * 4 + 2) * 512 + lane * 8] = B2;                \
    *(uint4*)&(BUF)[8192 + (w * 4 + 3) * 512 + lane * 8] = B3;                \
  } while (0)

#define GBURST(BUF)                                                           \
  do {                                                                        \
    const ushort* sAc = (BUF);                                                \
    const ushort* sBc = (BUF) + 8192;                                         \
    _Pragma("unroll")                                                         \
    for (int ks = 0; ks < 2; ++ks) {                                          \
      short8 av[4], bv[4];                                                    \
      _Pragma("unroll")                                                       \
      for (int mi = 0; mi < 4; ++mi) {                                        \
        const int row_ = wr * 64 + mi * 16 + l15;                             \
        av[mi] = *(const short8*)&sAc[row_ * 64 +                             \
                                      ((((ks * 4 + quad) ^ rsw)) << 3)];      \
      }                                                                       \
      _Pragma("unroll")                                                       \
      for (int ni = 0; ni < 4; ++ni) {                                        \
        const int row_ = wc * 64 + ni * 16 + l15;                             \
        bv[ni] = *(const short8*)&sBc[row_ * 64 +                             \
                                      ((((ks * 4 + quad) ^ rsw)) << 3)];      \
      }                                                                       \
      _Pragma("unroll")                                                       \
      for (int mi = 0; mi < 4; ++mi)                                          \
        _Pragma("unroll")                                                     \
        for (int ni = 0; ni < 4; ++ni)                                        \
          pacc[mi][ni] = MFMA(av[mi], bv[ni], pacc[mi][ni]);                  \
    }                                                                         \
  } while (0)

__global__ __launch_bounds__(512, 2)
void gemm_main(const ushort* __restrict__ Mws, const ushort* __restrict__ yt,
               float* __restrict__ out, int NR, int bq0, int ntcnt) {
  __shared__ __align__(16) ushort smem[49152];  // buf0 | buf1 (48KB each... 24576 ushorts)
  const int tid = threadIdx.x, lane = tid & 63, w = tid >> 6;
  const int wr = w >> 2, wc = w & 3;            // 2 x 4 wave grid
  const int quad = lane >> 4, l15 = lane & 15, rsw = l15 & 7;

  // XCD-bijective swizzle (gridDim.x % 8 == 0): XCD gets contiguous works,
  // works ordered ut-fastest -> 8 ut-blocks of one (t,nt) share B in L2.
  const int nb = (int)gridDim.x;
  const int swz = ((int)blockIdx.x & 7) * (nb >> 3) + ((int)blockIdx.x >> 3);
  const int ut = swz & 7;
  const int g = swz >> 3;
  const int nt = g % ntcnt;
  const int t = g / ntcnt;
  const int u0 = ut * 128, n0 = nt * 256;

  ushort* buf0 = smem;
  ushort* buf1 = smem + 24576;

  const int srow = lane >> 3;
  const int gchunk = (lane & 7) ^ srow;   // pre-swizzled source chunk

  // per-thread global base addresses (element offsets)
  const size_t ytk = (size_t)12 * (size_t)NR * 1024;  // yt k-slab stride
  const size_t aA0 = ((size_t)(t * 3) << 20) +
                     ((size_t)(u0 + (w * 2 + 0) * 8 + srow) << 10) + gchunk * 8;
  const size_t aA1 = ((size_t)(t * 3) << 20) +
                     ((size_t)(u0 + (w * 2 + 1) * 8 + srow) << 10) + gchunk * 8;
  const size_t bbase = ((size_t)t * (size_t)NR + n0) << 10;
  const size_t bB0 = bbase + ((size_t)((w * 4 + 0) * 8 + srow) << 10) + gchunk * 8;
  const size_t bB1 = bbase + ((size_t)((w * 4 + 1) * 8 + srow) << 10) + gchunk * 8;
  const size_t bB2 = bbase + ((size_t)((w * 4 + 2) * 8 + srow) << 10) + gchunk * 8;
  const size_t bB3 = bbase + ((size_t)((w * 4 + 3) * 8 + srow) << 10) + gchunk * 8;

  f32x4 pacc[4][4];
#pragma unroll
  for (int i = 0; i < 4; ++i)
#pragma unroll
    for (int j = 0; j < 4; ++j) pacc[i][j] = f32x4{0.f, 0.f, 0.f, 0.f};

  uint4 pa0, pa1, pb0, pb1, pb2, pb3;
  uint4 qa0, qa1, qb0, qb1, qb2, qb3;

  // prologue: chunk 0 -> buf0
  LOADCH(pa0, pa1, pb0, pb1, pb2, pb3, 0);
  WRITECH(pa0, pa1, pb0, pb1, pb2, pb3, buf0);
  __syncthreads();

#pragma unroll 1
  for (int it = 0; it < 24; ++it) {
    const int c1 = it * 2 + 1;
    // even chunk (buf0): issue c1 loads early, burst, commit c1 -> buf1
    LOADCH(qa0, qa1, qb0, qb1, qb2, qb3, c1);
    __builtin_amdgcn_s_setprio(1);
    GBURST(buf0);
    __builtin_amdgcn_s_setprio(0);
    WRITECH(qa0, qa1, qb0, qb1, qb2, qb3, buf1);
    __syncthreads();
    // odd chunk (buf1): issue c1+1 early, burst, commit -> buf0
    if (c1 < 47) LOADCH(pa0, pa1, pb0, pb1, pb2, pb3, c1 + 1);
    __builtin_amdgcn_s_setprio(1);
    GBURST(buf1);
    __builtin_amdgcn_s_setprio(0);
    if (c1 < 47) WRITECH(pa0, pa1, pb0, pb1, pb2, pb3, buf0);
    __syncthreads();
  }

  // epilogue: relu + f32 store
  const int ubase = u0 + wr * 64;
  const int nbase = n0 + wc * 64;
#pragma unroll
  for (int mi = 0; mi < 4; ++mi)
#pragma unroll
    for (int ni = 0; ni < 4; ++ni) {
      const int n = nbase + ni * 16 + l15;
      const int b = bq0 + (n >> 6), o = n & 63;
      float* op = out + (((size_t)b * 12 + t) * 1000) * 64 + o;
#pragma unroll
      for (int r = 0; r < 4; ++r) {
        const int u = ubase + mi * 16 + quad * 4 + r;
        if (u < 1000) op[(size_t)u * 64] = fmaxf(pacc[mi][ni][r], 0.f);
      }
    }
}

// ---------------------------------------------------------------------------
extern "C" void kernel_launch(void* const* d_in, const int* in_sizes, int n_in,
                              void* d_out, int out_size, void* d_ws, size_t ws_size,
                              hipStream_t stream) {
  const float* x     = (const float*)d_in[0];
  const float* Att   = (const float*)d_in[1];
  const float* cheb  = (const float*)d_in[2];
  const float* Theta = (const float*)d_in[3];
  float* out = (float*)d_out;

  ushort* Mws = (ushort*)d_ws;           // 75.5 MB row-major padded M
  ushort* yt  = Mws + 37748736ull;       // yt region

  build_m<<<147456, 256, 0, stream>>>(Att, cheb, Mws);

  if (ws_size >= 226492416ull) {
    // full path: yt [3][12][2048][1024] bf16 (144MB)
    build_yt<<<dim3(2, 12, 32), 192, 0, stream>>>(x, Theta, yt, 2048, 0);
    gemm_main<<<768, 512, 0, stream>>>(Mws, yt, out, 2048, 0, 8);
  } else {
    // quarter path: 4 passes of 8 batches, yt [3][12][512][1024] (36MB)
    for (int qq = 0; qq < 4; ++qq) {
      build_yt<<<dim3(2, 12, 8), 192, 0, stream>>>(x, Theta, yt, 512, qq * 8);
      gemm_main<<<192, 512, 0, stream>>>(Mws, yt, out, 512, qq * 8, 2);
    }
  }
}